// Round 1
// baseline (115.613 us; speedup 1.0000x reference)
//
#include <hip/hip_runtime.h>
#include <hip/hip_bf16.h>

#define BB 8
#define NN 16384
#define D1 256
#define D2 64
#define DT 320
#define EPSF 1e-12f

typedef __attribute__((ext_vector_type(8))) short bf16x8;
typedef __attribute__((ext_vector_type(4))) float f32x4;

__device__ __forceinline__ unsigned short f2bf(float f) {
    __hip_bfloat16 h = __float2bfloat16(f);
    return __builtin_bit_cast(unsigned short, h);
}

// swizzled ushort index into xt[DT][64]: XOR n-index with (c&7)<<3
__device__ __forceinline__ int swz(int c, int n) {
    return c * 64 + (n ^ ((c & 7) << 3));
}

// ---------------- kernel 1: s[b,c] = sum_n Y[b,n,c] ----------------
__global__ void colsum_kernel(const float* __restrict__ Y, float* __restrict__ s) {
    const int b = blockIdx.y;
    const int chunk = blockIdx.x;          // 0..31, 512 rows each
    const int t = threadIdx.x;             // 256
    const int c = t & 63;
    const int r = t >> 6;                  // 0..3
    const float* Yb = Y + (size_t)b * NN * D2;
    float acc = 0.f;
    const int nbase = chunk * 512;
    for (int k = 0; k < 128; ++k) {
        int n = nbase + k * 4 + r;
        acc += Yb[(size_t)n * D2 + c];
    }
    __shared__ float red[256];
    red[t] = acc;
    __syncthreads();
    if (r == 0) {
        float v = red[c] + red[64 + c] + red[128 + c] + red[192 + c];
        atomicAdd(&s[b * D2 + c], v);
    }
}

// ---------------- kernel 2: rsd[b,n] = (Y[b,n,:].s[b,:] + eps)^(-1/4) ----------------
__global__ void rsd_kernel(const float* __restrict__ Y, const float* __restrict__ s,
                           float* __restrict__ rsd) {
    const int blk = blockIdx.x;            // 2048 blocks
    const int b = blk >> 8;                // 256 blocks per batch
    const int nb = (blk & 255) * 64;
    const int t = threadIdx.x;             // 256
    const int q = t & 3;
    const int nl = t >> 2;                 // 0..63
    __shared__ float ss[D2];
    if (t < D2) ss[t] = s[b * D2 + t];
    __syncthreads();
    const int n = nb + nl;
    const float* yrow = Y + (size_t)b * NN * D2 + (size_t)n * D2 + q * 16;
    float dot = 0.f;
#pragma unroll
    for (int i = 0; i < 4; ++i) {
        float4 f = *reinterpret_cast<const float4*>(yrow + i * 4);
        const float* sp = ss + q * 16 + i * 4;
        dot += f.x * sp[0] + f.y * sp[1] + f.z * sp[2] + f.w * sp[3];
    }
    dot += __shfl_xor(dot, 1);
    dot += __shfl_xor(dot, 2);
    if (q == 0) {
        rsd[(size_t)b * NN + n] = rsqrtf(sqrtf(dot + EPSF));
    }
}

// ---------------- kernel 3: partial Gram G[b] += X^T X over an N-chunk ----------------
// grid (16 chunkgroups, 2 bands, 8 batches), 512 threads (8 waves: 2x4 tile grid)
__global__ void __launch_bounds__(512, 2)
gram_kernel(const float* __restrict__ V, const float* __restrict__ Y,
            const float* __restrict__ rsd, float* __restrict__ G) {
    const int cg = blockIdx.x;     // 0..15
    const int band = blockIdx.y;   // 0..1
    const int b = blockIdx.z;
    const int t = threadIdx.x;
    const int lane = t & 63;
    const int wid = t >> 6;        // 0..7
    const int wrow = wid >> 2;     // 0..1
    const int wcol = wid & 3;      // 0..3

    const float* Vb = V + (size_t)b * NN * D1;
    const float* Yb = Y + (size_t)b * NN * D2;
    const float* rb = rsd + (size_t)b * NN;

    __shared__ __attribute__((aligned(16))) unsigned short xt[DT * 64];  // 40 KB

    f32x4 acc[5][5];
#pragma unroll
    for (int i = 0; i < 5; ++i)
#pragma unroll
        for (int j = 0; j < 5; ++j)
            acc[i][j] = (f32x4){0.f, 0.f, 0.f, 0.f};

    const int g = t & 7;           // staging col-phase
    const int nl = t >> 3;         // staging row 0..63
    const int l15 = lane & 15;
    const int l4 = lane >> 4;

    for (int cc = 0; cc < 16; ++cc) {
        const int n0 = cg * 1024 + cc * 64;
        const int n = n0 + nl;
        __syncthreads();
        {
            const float r = rb[n];
            const float* vrow = Vb + (size_t)n * D1;
#pragma unroll
            for (int i2 = 0; i2 < 16; ++i2) {
                const int c0 = 2 * g + 16 * i2;
                float2 f = *reinterpret_cast<const float2*>(vrow + c0);
                xt[swz(c0, nl)]     = f2bf(f.x * r);
                xt[swz(c0 + 1, nl)] = f2bf(f.y * r);
            }
            const float* yrow = Yb + (size_t)n * D2;
#pragma unroll
            for (int i2 = 0; i2 < 4; ++i2) {
                const int c0 = 2 * g + 16 * i2;
                float2 f = *reinterpret_cast<const float2*>(yrow + c0);
                xt[swz(D1 + c0, nl)]     = f2bf(f.x * r);
                xt[swz(D1 + c0 + 1, nl)] = f2bf(f.y * r);
            }
        }
        __syncthreads();
#pragma unroll
        for (int ks = 0; ks < 2; ++ks) {
            const int noff = ks * 32 + 8 * l4;
            bf16x8 af[5], bfr[5];
#pragma unroll
            for (int i = 0; i < 5; ++i) {
                const int ca = band * 160 + wrow * 80 + i * 16 + l15;
                af[i] = *reinterpret_cast<const bf16x8*>(&xt[swz(ca, noff)]);
                const int cb = wcol * 80 + i * 16 + l15;
                bfr[i] = *reinterpret_cast<const bf16x8*>(&xt[swz(cb, noff)]);
            }
#pragma unroll
            for (int i = 0; i < 5; ++i)
#pragma unroll
                for (int j = 0; j < 5; ++j)
                    acc[i][j] = __builtin_amdgcn_mfma_f32_16x16x32_bf16(
                        af[i], bfr[j], acc[i][j], 0, 0, 0);
        }
    }

    // epilogue: atomic accumulate into G
    float* Gb = G + (size_t)b * DT * DT;
#pragma unroll
    for (int i = 0; i < 5; ++i) {
        const int gi_base = band * 160 + wrow * 80 + i * 16 + l4 * 4;
#pragma unroll
        for (int j = 0; j < 5; ++j) {
            const int gj = wcol * 80 + j * 16 + l15;
#pragma unroll
            for (int rg = 0; rg < 4; ++rg) {
                atomicAdd(&Gb[(size_t)(gi_base + rg) * DT + gj], acc[i][j][rg]);
            }
        }
    }
}

// ---------------- kernel 4: loss = mean_b sum_ij w(i,j) G^2 ----------------
__global__ void loss_kernel(const float* __restrict__ G, float* __restrict__ out) {
    const int b = blockIdx.x >> 3;
    const int slice = blockIdx.x & 7;
    const int t = threadIdx.x;  // 256
    const float* Gb = G + (size_t)b * DT * DT;
    float sum = 0.f;
    for (int k = 0; k < 50; ++k) {
        const int e = slice * 12800 + k * 256 + t;
        const int i = e / DT;
        const int j = e - i * DT;
        const float gv = Gb[e];
        const float w = ((i < D1) == (j < D1)) ? 1.f : -1.f;
        sum += w * gv * gv;
    }
#pragma unroll
    for (int off = 1; off < 64; off <<= 1) sum += __shfl_xor(sum, off);
    __shared__ float red[4];
    const int wid = t >> 6;
    if ((t & 63) == 0) red[wid] = sum;
    __syncthreads();
    if (t == 0) {
        float tot = red[0] + red[1] + red[2] + red[3];
        atomicAdd(out, tot * 0.125f);
    }
}

extern "C" void kernel_launch(void* const* d_in, const int* in_sizes, int n_in,
                              void* d_out, int out_size, void* d_ws, size_t ws_size,
                              hipStream_t stream) {
    const float* V = (const float*)d_in[0];
    const float* Y = (const float*)d_in[1];
    float* out = (float*)d_out;

    char* ws = (char*)d_ws;
    float* s   = (float*)ws;                          // 512 floats
    float* G   = (float*)(ws + 2048);                 // 8*320*320 floats = 3,276,800 B
    float* rsd = (float*)(ws + 2048 + 3276800);       // 131072 floats

    hipMemsetAsync(d_ws, 0, 2048 + 3276800, stream);
    hipMemsetAsync(d_out, 0, sizeof(float), stream);

    colsum_kernel<<<dim3(32, BB), 256, 0, stream>>>(Y, s);
    rsd_kernel<<<2048, 256, 0, stream>>>(Y, s, rsd);
    gram_kernel<<<dim3(16, 2, BB), 512, 0, stream>>>(V, Y, rsd, G);
    loss_kernel<<<64, 256, 0, stream>>>(G, out);
}

// Round 2
// 114.707 us; speedup vs baseline: 1.0079x; 1.0079x over previous
//
#include <hip/hip_runtime.h>
#include <hip/hip_bf16.h>

#define BB 8
#define NN 16384
#define D1 256
#define D2 64
#define DT 320
#define EPSF 1e-12f

typedef __attribute__((ext_vector_type(8))) short bf16x8;
typedef __attribute__((ext_vector_type(4))) float f32x4;
typedef __attribute__((ext_vector_type(4))) unsigned int u32x4;

__device__ __forceinline__ unsigned int packbf2(float a, float b) {
    unsigned short lo = __builtin_bit_cast(unsigned short, __float2bfloat16(a));
    unsigned short hi = __builtin_bit_cast(unsigned short, __float2bfloat16(b));
    return (unsigned int)lo | ((unsigned int)hi << 16);
}

// ---------------- kernel 1: s[b,c] = sum_n Y[b,n,c] ----------------
__global__ void colsum_kernel(const float* __restrict__ Y, float* __restrict__ s) {
    const int b = blockIdx.y;
    const int chunk = blockIdx.x;          // 0..31, 512 rows each
    const int t = threadIdx.x;             // 256
    const int c = t & 63;
    const int r = t >> 6;                  // 0..3
    const float* Yb = Y + (size_t)b * NN * D2;
    float acc = 0.f;
    const int nbase = chunk * 512;
    for (int k = 0; k < 128; ++k) {
        int n = nbase + k * 4 + r;
        acc += Yb[(size_t)n * D2 + c];
    }
    __shared__ float red[256];
    red[t] = acc;
    __syncthreads();
    if (r == 0) {
        float v = red[c] + red[64 + c] + red[128 + c] + red[192 + c];
        atomicAdd(&s[b * D2 + c], v);
    }
}

// ---------------- kernel 2: rsd[b,n] = (Y[b,n,:].s[b,:] + eps)^(-1/4) ----------------
__global__ void rsd_kernel(const float* __restrict__ Y, const float* __restrict__ s,
                           float* __restrict__ rsd) {
    const int blk = blockIdx.x;            // 2048 blocks
    const int b = blk >> 8;                // 256 blocks per batch
    const int nb = (blk & 255) * 64;
    const int t = threadIdx.x;             // 256
    const int q = t & 3;
    const int nl = t >> 2;                 // 0..63
    __shared__ float ss[D2];
    if (t < D2) ss[t] = s[b * D2 + t];
    __syncthreads();
    const int n = nb + nl;
    const float* yrow = Y + (size_t)b * NN * D2 + (size_t)n * D2 + q * 16;
    float dot = 0.f;
#pragma unroll
    for (int i = 0; i < 4; ++i) {
        float4 f = *reinterpret_cast<const float4*>(yrow + i * 4);
        const float* sp = ss + q * 16 + i * 4;
        dot += f.x * sp[0] + f.y * sp[1] + f.z * sp[2] + f.w * sp[3];
    }
    dot += __shfl_xor(dot, 1);
    dot += __shfl_xor(dot, 2);
    if (q == 0) {
        rsd[(size_t)b * NN + n] = rsqrtf(sqrtf(dot + EPSF));
    }
}

// ---------------- kernel 3 helpers ----------------
__device__ __forceinline__ void issue_loads(const float* __restrict__ Vb,
                                            const float* __restrict__ Yb,
                                            const float* __restrict__ rb,
                                            int n0w, int lane,
                                            float4* vf, float4* yf, float* rr) {
#pragma unroll
    for (int j = 0; j < 8; ++j)
        vf[j] = *reinterpret_cast<const float4*>(Vb + (size_t)(n0w + j) * D1 + 4 * lane);
    const int j2 = lane >> 4, k15 = lane & 15;
    yf[0] = *reinterpret_cast<const float4*>(Yb + (size_t)(n0w + 2 * j2) * D2 + 4 * k15);
    yf[1] = *reinterpret_cast<const float4*>(Yb + (size_t)(n0w + 2 * j2 + 1) * D2 + 4 * k15);
#pragma unroll
    for (int j = 0; j < 8; ++j) rr[j] = rb[n0w + j];
}

__device__ __forceinline__ void write_tile(unsigned short* __restrict__ x,
                                           int lane, int w,
                                           const float4* vf, const float4* yf,
                                           const float* rr) {
    const float* vfp = reinterpret_cast<const float*>(vf);
    const float* yfp = reinterpret_cast<const float*>(yf);
    // V columns: c = 4*lane + cidx; unit n8 = w
    const int phiV = (w ^ lane) & 7;
#pragma unroll
    for (int cidx = 0; cidx < 4; ++cidx) {
        const int c = 4 * lane + cidx;
        u32x4 p;
        p[0] = packbf2(vfp[0 * 4 + cidx] * rr[0], vfp[1 * 4 + cidx] * rr[1]);
        p[1] = packbf2(vfp[2 * 4 + cidx] * rr[2], vfp[3 * 4 + cidx] * rr[3]);
        p[2] = packbf2(vfp[4 * 4 + cidx] * rr[4], vfp[5 * 4 + cidx] * rr[5]);
        p[3] = packbf2(vfp[6 * 4 + cidx] * rr[6], vfp[7 * 4 + cidx] * rr[7]);
        *reinterpret_cast<u32x4*>(&x[c * 64 + phiV * 8]) = p;
    }
    // Y columns: c = D1 + 4*k15 + cidx; rows (2*j2, 2*j2+1) -> u32 slot j2
    const int j2 = lane >> 4, k15 = lane & 15;
    const float r0 = rr[2 * j2], r1 = rr[2 * j2 + 1];
    const int phiY = (w ^ k15) & 7;
#pragma unroll
    for (int cidx = 0; cidx < 4; ++cidx) {
        const int c = D1 + 4 * k15 + cidx;
        unsigned int p = packbf2(yfp[0 * 4 + cidx] * r0, yfp[1 * 4 + cidx] * r1);
        *reinterpret_cast<unsigned int*>(&x[c * 64 + phiY * 8 + j2 * 2]) = p;
    }
}

// ---------------- kernel 3: partial Gram G[b] += X^T X over an N-chunk ----------------
// grid (16 chunkgroups, 2 bands, 8 batches) = 256 blocks, 512 threads (8 waves: 2x4 tiles)
__global__ void __launch_bounds__(512, 2)
gram_kernel(const float* __restrict__ V, const float* __restrict__ Y,
            const float* __restrict__ rsd, float* __restrict__ G) {
    const int cg = blockIdx.x;     // 0..15
    const int band = blockIdx.y;   // 0..1
    const int b = blockIdx.z;
    const int t = threadIdx.x;
    const int lane = t & 63;
    const int w = t >> 6;          // 0..7
    const int wrow = w >> 2;       // 0..1
    const int wcol = w & 3;        // 0..3
    const int l15 = lane & 15;
    const int l4 = lane >> 4;

    const float* Vb = V + (size_t)b * NN * D1;
    const float* Yb = Y + (size_t)b * NN * D2;
    const float* rb = rsd + (size_t)b * NN;

    // double-buffered transposed bf16 tile: xt[buf] is [c=0..319][16B units x 8]
    __shared__ __attribute__((aligned(16))) unsigned short xt[2][DT * 64];  // 80 KB

    f32x4 acc[5][5];
#pragma unroll
    for (int i = 0; i < 5; ++i)
#pragma unroll
        for (int j = 0; j < 5; ++j)
            acc[i][j] = (f32x4){0.f, 0.f, 0.f, 0.f};

    float4 vf[8];
    float4 yf[2];
    float rr[8];

    const int n0base = cg * 1024;

    // prologue: stage tile 0
    issue_loads(Vb, Yb, rb, n0base + 8 * w, lane, vf, yf, rr);
    write_tile(xt[0], lane, w, vf, yf, rr);
    __syncthreads();

    for (int tt = 0; tt < 16; ++tt) {
        if (tt < 15)
            issue_loads(Vb, Yb, rb, n0base + (tt + 1) * 64 + 8 * w, lane, vf, yf, rr);

        const unsigned short* x = xt[tt & 1];
#pragma unroll
        for (int ks = 0; ks < 2; ++ks) {
            const int n8r = 2 * l4 + ks;   // K-block remap: A and B agree -> valid
            bf16x8 af[5], bfr[5];
#pragma unroll
            for (int i = 0; i < 5; ++i) {
                const int ca = band * 160 + wrow * 80 + i * 16 + l15;
                af[i] = *reinterpret_cast<const bf16x8*>(
                    &x[ca * 64 + ((n8r ^ (ca >> 2)) & 7) * 8]);
                const int cb = wcol * 80 + i * 16 + l15;
                bfr[i] = *reinterpret_cast<const bf16x8*>(
                    &x[cb * 64 + ((n8r ^ (cb >> 2)) & 7) * 8]);
            }
#pragma unroll
            for (int i = 0; i < 5; ++i)
#pragma unroll
                for (int j = 0; j < 5; ++j)
                    acc[i][j] = __builtin_amdgcn_mfma_f32_16x16x32_bf16(
                        af[i], bfr[j], acc[i][j], 0, 0, 0);
        }

        if (tt < 15)
            write_tile(xt[(tt + 1) & 1], lane, w, vf, yf, rr);
        __syncthreads();
    }

    // epilogue: atomic accumulate into G (verified mapping)
    float* Gb = G + (size_t)b * DT * DT;
#pragma unroll
    for (int i = 0; i < 5; ++i) {
        const int gi_base = band * 160 + wrow * 80 + i * 16 + l4 * 4;
#pragma unroll
        for (int j = 0; j < 5; ++j) {
            const int gj = wcol * 80 + j * 16 + l15;
#pragma unroll
            for (int rg = 0; rg < 4; ++rg) {
                atomicAdd(&Gb[(size_t)(gi_base + rg) * DT + gj], acc[i][j][rg]);
            }
        }
    }
}

// ---------------- kernel 4: loss = mean_b sum_ij w(i,j) G^2 ----------------
__global__ void loss_kernel(const float* __restrict__ G, float* __restrict__ out) {
    const int b = blockIdx.x >> 3;
    const int slice = blockIdx.x & 7;
    const int t = threadIdx.x;  // 256
    const float* Gb = G + (size_t)b * DT * DT;
    float sum = 0.f;
    for (int k = 0; k < 50; ++k) {
        const int e = slice * 12800 + k * 256 + t;
        const int i = e / DT;
        const int j = e - i * DT;
        const float gv = Gb[e];
        const float w = ((i < D1) == (j < D1)) ? 1.f : -1.f;
        sum += w * gv * gv;
    }
#pragma unroll
    for (int off = 1; off < 64; off <<= 1) sum += __shfl_xor(sum, off);
    __shared__ float red[4];
    const int wid = t >> 6;
    if ((t & 63) == 0) red[wid] = sum;
    __syncthreads();
    if (t == 0) {
        float tot = red[0] + red[1] + red[2] + red[3];
        atomicAdd(out, tot * 0.125f);
    }
}

extern "C" void kernel_launch(void* const* d_in, const int* in_sizes, int n_in,
                              void* d_out, int out_size, void* d_ws, size_t ws_size,
                              hipStream_t stream) {
    const float* V = (const float*)d_in[0];
    const float* Y = (const float*)d_in[1];
    float* out = (float*)d_out;

    char* ws = (char*)d_ws;
    float* s   = (float*)ws;                          // 512 floats
    float* G   = (float*)(ws + 2048);                 // 8*320*320 floats
    float* rsd = (float*)(ws + 2048 + 3276800);       // 131072 floats

    hipMemsetAsync(d_ws, 0, 2048 + 3276800, stream);
    hipMemsetAsync(d_out, 0, sizeof(float), stream);

    colsum_kernel<<<dim3(32, BB), 256, 0, stream>>>(Y, s);
    rsd_kernel<<<2048, 256, 0, stream>>>(Y, s, rsd);
    gram_kernel<<<dim3(16, 2, BB), 512, 0, stream>>>(V, Y, rsd, G);
    loss_kernel<<<64, 256, 0, stream>>>(G, out);
}

// Round 3
// 90.346 us; speedup vs baseline: 1.2797x; 1.2696x over previous
//
#include <hip/hip_runtime.h>
#include <hip/hip_bf16.h>

#define BB 8
#define NN 16384
#define D1 256
#define D2 64
#define DT 320
#define EPSF 1e-12f

typedef __attribute__((ext_vector_type(8))) short bf16x8;
typedef __attribute__((ext_vector_type(4))) float f32x4;
typedef __attribute__((ext_vector_type(4))) unsigned int u32x4;

__device__ __forceinline__ unsigned int packbf2(float a, float b) {
    unsigned short lo = __builtin_bit_cast(unsigned short, __float2bfloat16(a));
    unsigned short hi = __builtin_bit_cast(unsigned short, __float2bfloat16(b));
    return (unsigned int)lo | ((unsigned int)hi << 16);
}

// swizzle: element (c, n8*8+k) lives at unit u = (n8 ^ sig(c)) & 7 of row c.
// sig is bijective over 8 consecutive c (frag reads: c = 16m + l15) AND over
// c = cidx + 4*l (staging writes) -> conflict-free b128 on both sides.
__device__ __forceinline__ int sig(int c) { return (c ^ (c >> 2)) & 7; }

// ---------------- kernel 1: s[b,c] = sum_n Y[b,n,c] ----------------
__global__ void colsum_kernel(const float* __restrict__ Y, float* __restrict__ s) {
    const int b = blockIdx.y;
    const int chunk = blockIdx.x;          // 0..31, 512 rows each
    const int t = threadIdx.x;             // 256
    const int c = t & 63;
    const int r = t >> 6;                  // 0..3
    const float* Yb = Y + (size_t)b * NN * D2;
    float acc = 0.f;
    const int nbase = chunk * 512;
    for (int k = 0; k < 128; ++k) {
        int n = nbase + k * 4 + r;
        acc += Yb[(size_t)n * D2 + c];
    }
    __shared__ float red[256];
    red[t] = acc;
    __syncthreads();
    if (r == 0) {
        float v = red[c] + red[64 + c] + red[128 + c] + red[192 + c];
        atomicAdd(&s[b * D2 + c], v);
    }
}

// ---------------- kernel 2: rsd[b,n] = (Y[b,n,:].s[b,:] + eps)^(-1/4) ----------------
__global__ void rsd_kernel(const float* __restrict__ Y, const float* __restrict__ s,
                           float* __restrict__ rsd) {
    const int blk = blockIdx.x;            // 2048 blocks
    const int b = blk >> 8;
    const int nb = (blk & 255) * 64;
    const int t = threadIdx.x;             // 256
    const int q = t & 3;
    const int nl = t >> 2;
    __shared__ float ss[D2];
    if (t < D2) ss[t] = s[b * D2 + t];
    __syncthreads();
    const int n = nb + nl;
    const float* yrow = Y + (size_t)b * NN * D2 + (size_t)n * D2 + q * 16;
    float dot = 0.f;
#pragma unroll
    for (int i = 0; i < 4; ++i) {
        float4 f = *reinterpret_cast<const float4*>(yrow + i * 4);
        const float* sp = ss + q * 16 + i * 4;
        dot += f.x * sp[0] + f.y * sp[1] + f.z * sp[2] + f.w * sp[3];
    }
    dot += __shfl_xor(dot, 1);
    dot += __shfl_xor(dot, 2);
    if (q == 0) {
        rsd[(size_t)b * NN + n] = rsqrtf(sqrtf(dot + EPSF));
    }
}

// ---------------- kernel 3 helpers ----------------
__device__ __forceinline__ void issue_loads(const float* __restrict__ Vb,
                                            const float* __restrict__ Yb,
                                            const float* __restrict__ rb,
                                            int n0w, int lane,
                                            float4* vf, float4* yf, float* rr) {
#pragma unroll
    for (int j = 0; j < 8; ++j)
        vf[j] = *reinterpret_cast<const float4*>(Vb + (size_t)(n0w + j) * D1 + 4 * lane);
    const int j2 = lane >> 4, k15 = lane & 15;
    yf[0] = *reinterpret_cast<const float4*>(Yb + (size_t)(n0w + 2 * j2) * D2 + 4 * k15);
    yf[1] = *reinterpret_cast<const float4*>(Yb + (size_t)(n0w + 2 * j2 + 1) * D2 + 4 * k15);
#pragma unroll
    for (int j = 0; j < 8; ++j) rr[j] = rb[n0w + j];
}

__device__ __forceinline__ void write_tile(unsigned short* __restrict__ x,
                                           int lane, int w,
                                           const float4* vf, const float4* yf,
                                           const float* rr) {
    const float* vfp = reinterpret_cast<const float*>(vf);
    const float* yfp = reinterpret_cast<const float*>(yf);
    // V columns: c = 4*lane + cidx; rows n8 = w (8 rows packed in one b128)
#pragma unroll
    for (int cidx = 0; cidx < 4; ++cidx) {
        const int c = 4 * lane + cidx;
        const int u = (w ^ sig(c)) & 7;
        u32x4 p;
        p[0] = packbf2(vfp[0 * 4 + cidx] * rr[0], vfp[1 * 4 + cidx] * rr[1]);
        p[1] = packbf2(vfp[2 * 4 + cidx] * rr[2], vfp[3 * 4 + cidx] * rr[3]);
        p[2] = packbf2(vfp[4 * 4 + cidx] * rr[4], vfp[5 * 4 + cidx] * rr[5]);
        p[3] = packbf2(vfp[6 * 4 + cidx] * rr[6], vfp[7 * 4 + cidx] * rr[7]);
        *reinterpret_cast<u32x4*>(&x[c * 64 + u * 8]) = p;
    }
    // Y columns: c = D1 + 4*k15 + cidx; rows (2*j2, 2*j2+1) -> u32 slot j2
    const int j2 = lane >> 4, k15 = lane & 15;
    const float r0 = rr[2 * j2], r1 = rr[2 * j2 + 1];
#pragma unroll
    for (int cidx = 0; cidx < 4; ++cidx) {
        const int c = D1 + 4 * k15 + cidx;
        const int u = (w ^ sig(c)) & 7;
        unsigned int p = packbf2(yfp[0 * 4 + cidx] * r0, yfp[1 * 4 + cidx] * r1);
        *reinterpret_cast<unsigned int*>(&x[c * 64 + u * 8 + j2 * 2]) = p;
    }
}

// ---------------- kernel 3: partial Gram over an N-chunk ----------------
// grid (16 cg, 2 bands, 8 batches) = 256 blocks, 512 threads (8 waves: 2x4 tiles)
__global__ void __launch_bounds__(512, 2)
gram_kernel(const float* __restrict__ V, const float* __restrict__ Y,
            const float* __restrict__ rsd, float* __restrict__ Gout, int priv) {
    const int cg = blockIdx.x;     // 0..15
    const int band = blockIdx.y;   // 0..1
    const int b = blockIdx.z;
    const int t = threadIdx.x;
    const int lane = t & 63;
    const int w = t >> 6;
    const int wrow = w >> 2;       // 0..1
    const int wcol = w & 3;        // 0..3
    const int l15 = lane & 15;
    const int l4 = lane >> 4;

    const float* Vb = V + (size_t)b * NN * D1;
    const float* Yb = Y + (size_t)b * NN * D2;
    const float* rb = rsd + (size_t)b * NN;

    __shared__ __attribute__((aligned(16))) unsigned short xt[2][DT * 64];  // 80 KB

    f32x4 acc[5][5];
#pragma unroll
    for (int i = 0; i < 5; ++i)
#pragma unroll
        for (int j = 0; j < 5; ++j)
            acc[i][j] = (f32x4){0.f, 0.f, 0.f, 0.f};

    float4 vf[8];
    float4 yf[2];
    float rr[8];

    const int n0base = cg * 1024;

    issue_loads(Vb, Yb, rb, n0base + 8 * w, lane, vf, yf, rr);
    write_tile(xt[0], lane, w, vf, yf, rr);
    __syncthreads();

    for (int tt = 0; tt < 16; ++tt) {
        if (tt < 15)
            issue_loads(Vb, Yb, rb, n0base + (tt + 1) * 64 + 8 * w, lane, vf, yf, rr);

        const unsigned short* x = xt[tt & 1];
#pragma unroll
        for (int ks = 0; ks < 2; ++ks) {
            const int n8r = 2 * l4 + ks;   // K-block remap, A/B consistent
            bf16x8 af[5], bfr[5];
#pragma unroll
            for (int i = 0; i < 5; ++i) {
                const int ca = band * 160 + wrow * 80 + i * 16 + l15;
                af[i] = *reinterpret_cast<const bf16x8*>(
                    &x[ca * 64 + ((n8r ^ sig(ca)) & 7) * 8]);
                const int cb = wcol * 80 + i * 16 + l15;
                bfr[i] = *reinterpret_cast<const bf16x8*>(
                    &x[cb * 64 + ((n8r ^ sig(cb)) & 7) * 8]);
            }
#pragma unroll
            for (int i = 0; i < 5; ++i)
#pragma unroll
                for (int j = 0; j < 5; ++j)
                    acc[i][j] = __builtin_amdgcn_mfma_f32_16x16x32_bf16(
                        af[i], bfr[j], acc[i][j], 0, 0, 0);
        }

        if (tt < 15)
            write_tile(xt[(tt + 1) & 1], lane, w, vf, yf, rr);
        __syncthreads();
    }

    if (priv) {
        // streaming store of this block's 160x320 partial into its private slice
        float* Gp = Gout + (size_t)(b * 16 + cg) * (DT * DT);
#pragma unroll
        for (int i = 0; i < 5; ++i) {
            const int gi_base = band * 160 + wrow * 80 + i * 16 + l4 * 4;
#pragma unroll
            for (int j = 0; j < 5; ++j) {
                const int gj = wcol * 80 + j * 16 + l15;
#pragma unroll
                for (int rg = 0; rg < 4; ++rg)
                    Gp[(size_t)(gi_base + rg) * DT + gj] = acc[i][j][rg];
            }
        }
    } else {
        float* Gb = Gout + (size_t)b * DT * DT;
#pragma unroll
        for (int i = 0; i < 5; ++i) {
            const int gi_base = band * 160 + wrow * 80 + i * 16 + l4 * 4;
#pragma unroll
            for (int j = 0; j < 5; ++j) {
                const int gj = wcol * 80 + j * 16 + l15;
#pragma unroll
                for (int rg = 0; rg < 4; ++rg)
                    atomicAdd(&Gb[(size_t)(gi_base + rg) * DT + gj], acc[i][j][rg]);
            }
        }
    }
}

// ---------------- kernel 4a: privatized loss reduce over 16 cg partials --------
__global__ void loss_priv_kernel(const float* __restrict__ Gpart, float* __restrict__ out) {
    const int b = blockIdx.y;
    const int slice = blockIdx.x;          // 0..99
    const int t = threadIdx.x;             // 256
    const int e0 = slice * 1024 + t * 4;   // float4-aligned element index
    float4 g = make_float4(0.f, 0.f, 0.f, 0.f);
#pragma unroll
    for (int cg = 0; cg < 16; ++cg) {
        float4 p = *reinterpret_cast<const float4*>(
            Gpart + (size_t)(b * 16 + cg) * (DT * DT) + e0);
        g.x += p.x; g.y += p.y; g.z += p.z; g.w += p.w;
    }
    const int i = e0 / DT;
    const int j = e0 - i * DT;             // all 4 elems same side of 256 (4-aligned)
    const float wgt = ((i < D1) == (j < D1)) ? 1.f : -1.f;
    float sum = wgt * (g.x * g.x + g.y * g.y + g.z * g.z + g.w * g.w);
#pragma unroll
    for (int off = 1; off < 64; off <<= 1) sum += __shfl_xor(sum, off);
    __shared__ float red[4];
    if ((t & 63) == 0) red[t >> 6] = sum;
    __syncthreads();
    if (t == 0) atomicAdd(out, (red[0] + red[1] + red[2] + red[3]) * 0.125f);
}

// ---------------- kernel 4b: fallback loss over accumulated G ----------------
__global__ void loss_kernel(const float* __restrict__ G, float* __restrict__ out) {
    const int b = blockIdx.x >> 3;
    const int slice = blockIdx.x & 7;
    const int t = threadIdx.x;
    const float* Gb = G + (size_t)b * DT * DT;
    float sum = 0.f;
    for (int k = 0; k < 50; ++k) {
        const int e = slice * 12800 + k * 256 + t;
        const int i = e / DT;
        const int j = e - i * DT;
        const float gv = Gb[e];
        const float w = ((i < D1) == (j < D1)) ? 1.f : -1.f;
        sum += w * gv * gv;
    }
#pragma unroll
    for (int off = 1; off < 64; off <<= 1) sum += __shfl_xor(sum, off);
    __shared__ float red[4];
    if ((t & 63) == 0) red[t >> 6] = sum;
    __syncthreads();
    if (t == 0) atomicAdd(out, (red[0] + red[1] + red[2] + red[3]) * 0.125f);
}

extern "C" void kernel_launch(void* const* d_in, const int* in_sizes, int n_in,
                              void* d_out, int out_size, void* d_ws, size_t ws_size,
                              hipStream_t stream) {
    const float* V = (const float*)d_in[0];
    const float* Y = (const float*)d_in[1];
    float* out = (float*)d_out;

    char* ws = (char*)d_ws;
    float* s    = (float*)ws;                         // 2048 B
    float* rsd  = (float*)(ws + 2048);                // 524288 B
    float* Gbuf = (float*)(ws + 2048 + 524288);       // priv: 52.4 MB / fallback: 3.28 MB

    const size_t need_priv = 2048 + 524288 + (size_t)BB * 16 * DT * DT * 4;
    const int priv = (ws_size >= need_priv) ? 1 : 0;

    hipMemsetAsync(s, 0, 2048, stream);
    if (!priv) hipMemsetAsync(Gbuf, 0, (size_t)BB * DT * DT * 4, stream);
    hipMemsetAsync(d_out, 0, sizeof(float), stream);

    colsum_kernel<<<dim3(32, BB), 256, 0, stream>>>(Y, s);
    rsd_kernel<<<2048, 256, 0, stream>>>(Y, s, rsd);
    gram_kernel<<<dim3(16, 2, BB), 512, 0, stream>>>(V, Y, rsd, Gbuf, priv);
    if (priv)
        loss_priv_kernel<<<dim3(100, BB), 256, 0, stream>>>(Gbuf, out);
    else
        loss_kernel<<<64, 256, 0, stream>>>(Gbuf, out);
}